// Round 2
// baseline (671.052 us; speedup 1.0000x reference)
//
#include <hip/hip_runtime.h>

#define N_NODES 100000
#define N_PAD   100096   // multiple of 64 for GEMM block tiles
#define N_EDGES 320000
#define NB      128
#define DIN     128
#define H       256
#define OUT_DIM 10
#define EPSV    1e-6f
#define SCAN_B  256
#define PSLICES 32

typedef unsigned short bf16_t;
typedef __attribute__((ext_vector_type(8))) short bf16x8;
typedef __attribute__((ext_vector_type(4))) float f32x4;

__device__ __forceinline__ float bf2f(bf16_t u) {
    union { unsigned int i; float f; } x;
    x.i = ((unsigned int)u) << 16;
    return x.f;
}
__device__ __forceinline__ bf16_t f2bf(float f) {
    union { float f; unsigned int i; } x;
    x.f = f;
    unsigned int r = x.i + 0x7fffu + ((x.i >> 16) & 1u);   // round-to-nearest-even
    return (bf16_t)(r >> 16);
}

// ---------------- degree ----------------
__global__ void k_edge_deg(const int* __restrict__ src, const int* __restrict__ dst,
                           int* deg_out, int* deg_in) {
    int e = blockIdx.x * blockDim.x + threadIdx.x;
    if (e < N_EDGES) {
        atomicAdd(&deg_out[src[e]], 1);
        atomicAdd(&deg_in[dst[e]], 1);
    }
}

__global__ void k_dinv(const int* __restrict__ deg_out, const int* __restrict__ deg_in,
                       float* dinv_src, float* dinv_dst) {
    int n = blockIdx.x * blockDim.x + threadIdx.x;
    if (n < N_NODES) {
        dinv_src[n] = rsqrtf((float)max(deg_out[n], 1));
        dinv_dst[n] = rsqrtf((float)max(deg_in[n], 1));
    }
}

// ---------------- graph offsets via binary search (bid is sorted) ----------------
__global__ void k_gstart(const int* __restrict__ bid, int* __restrict__ gstart,
                         float* __restrict__ countsf) {
    int b = threadIdx.x;
    if (b <= NB) {
        int lo = 0, hi = N_NODES;
        while (lo < hi) {
            int mid = (lo + hi) >> 1;
            if (bid[mid] < b) lo = mid + 1; else hi = mid;
        }
        gstart[b] = lo;
    }
    __syncthreads();
    if (b < NB) countsf[b] = (float)max(gstart[b + 1] - gstart[b], 1);
}

// ---------------- hierarchical scan for CSR row_start ----------------
__global__ void k_scan1(const int* __restrict__ deg, int* incl, int* bsums) {
    __shared__ int s[SCAN_B];
    int i = blockIdx.x * SCAN_B + threadIdx.x;
    int v = (i < N_NODES) ? deg[i] : 0;
    s[threadIdx.x] = v;
    __syncthreads();
    for (int d = 1; d < SCAN_B; d <<= 1) {
        int t = (threadIdx.x >= d) ? s[threadIdx.x - d] : 0;
        __syncthreads();
        s[threadIdx.x] += t;
        __syncthreads();
    }
    if (i < N_NODES) incl[i] = s[threadIdx.x];
    if (threadIdx.x == SCAN_B - 1) bsums[blockIdx.x] = s[threadIdx.x];
}

__global__ void k_scan2(const int* __restrict__ bsums, int* boffs, int nb) {
    __shared__ int s[512];
    int t = threadIdx.x;
    int v = (t < nb) ? bsums[t] : 0;
    s[t] = v;
    __syncthreads();
    for (int d = 1; d < 512; d <<= 1) {
        int x = (t >= d) ? s[t - d] : 0;
        __syncthreads();
        s[t] += x;
        __syncthreads();
    }
    if (t < nb) boffs[t] = s[t] - v;   // exclusive
}

__global__ void k_scan3(const int* __restrict__ deg, const int* __restrict__ incl,
                        const int* __restrict__ boffs, int* row_start, int* cursor) {
    int i = blockIdx.x * blockDim.x + threadIdx.x;
    if (i < N_NODES) {
        int ex = incl[i] - deg[i] + boffs[i / SCAN_B];
        row_start[i] = ex;
        cursor[i]    = ex;
    }
    if (i == 0) row_start[N_NODES] = N_EDGES;
}

__global__ void k_scatter(const int* __restrict__ src, const int* __restrict__ dst,
                          int* cursor, int* csr_src) {
    int e = blockIdx.x * blockDim.x + threadIdx.x;
    if (e < N_EDGES) {
        int slot = atomicAdd(&cursor[dst[e]], 1);
        csr_src[slot] = src[e];
    }
}

// ---------------- weight convert + transpose: Wt[c][k] = bf16(W[k][c]) ----------------
__global__ void k_wt_first(const float* __restrict__ W, bf16_t* __restrict__ Wt) {
    int idx = blockIdx.x * 256 + threadIdx.x;   // idx = c*DIN + k
    if (idx >= H * DIN) return;
    int c = idx / DIN, k = idx % DIN;
    Wt[idx] = f2bf(W[k * H + c]);
}
__global__ void k_wt_rest(const float* __restrict__ W, bf16_t* __restrict__ Wt) {
    int idx = blockIdx.x * 256 + threadIdx.x;   // idx = l*H*H + c*H + k
    if (idx >= 3 * H * H) return;
    int l = idx / (H * H);
    int rem = idx % (H * H);
    int c = rem / H, k = rem % H;
    Wt[idx] = f2bf(W[(size_t)l * H * H + k * H + c]);
}

// ---------------- layer-0 prescale: hs[n][c] = bf16(h[n][c] * dinv_src[n]) ----------------
__global__ void k_prescale(const float* __restrict__ h, const float* __restrict__ dinv_s,
                           bf16_t* __restrict__ hs) {
    int idx = blockIdx.x * blockDim.x + threadIdx.x;   // over N * DIN/4
    if (idx >= N_NODES * (DIN / 4)) return;
    int n = idx >> 5;                                  // DIN/4 = 32
    float w = dinv_s[n];
    float4 v = reinterpret_cast<const float4*>(h)[idx];
    ushort4 o;
    o.x = f2bf(v.x * w); o.y = f2bf(v.y * w);
    o.z = f2bf(v.z * w); o.w = f2bf(v.w * w);
    reinterpret_cast<ushort4*>(hs)[idx] = o;
}

// ---------------- aggregation: one wave per node, CSR by dst ----------------
template <int NC, bool PS>
__global__ void k_agg(const bf16_t* __restrict__ hx, const float* __restrict__ dinv_s,
                      const float* __restrict__ dinv_d, const int* __restrict__ row_start,
                      const int* __restrict__ csr_src, bf16_t* __restrict__ m) {
    constexpr int VEC = NC / 64;     // ushorts per lane (2 or 4)
    int gid  = blockIdx.x * blockDim.x + threadIdx.x;
    int v    = gid >> 6;
    int lane = gid & 63;
    if (v >= N_NODES) return;
    float acc[VEC] = {};
    int s0 = row_start[v], s1 = row_start[v + 1];

    auto body = [&](int ei) {
        int si = csr_src[ei];
        float wv = 1.f;
        if constexpr (!PS) wv = dinv_s[si];
        if constexpr (VEC == 4) {
            ushort4 r = *reinterpret_cast<const ushort4*>(hx + (size_t)si * NC + lane * 4);
            acc[0] += bf2f(r.x) * wv; acc[1] += bf2f(r.y) * wv;
            acc[2] += bf2f(r.z) * wv; acc[3] += bf2f(r.w) * wv;
        } else {
            ushort2 r = *reinterpret_cast<const ushort2*>(hx + (size_t)si * NC + lane * 2);
            acc[0] += bf2f(r.x) * wv; acc[1] += bf2f(r.y) * wv;
        }
    };

    int e = s0;
    for (; e + 3 < s1; e += 4) { body(e); body(e + 1); body(e + 2); body(e + 3); }
    for (; e < s1; ++e) body(e);

    float wd = dinv_d[v];
    if constexpr (VEC == 4) {
        ushort4 o;
        o.x = f2bf(acc[0] * wd); o.y = f2bf(acc[1] * wd);
        o.z = f2bf(acc[2] * wd); o.w = f2bf(acc[3] * wd);
        *reinterpret_cast<ushort4*>(m + (size_t)v * NC + lane * 4) = o;
    } else {
        ushort2 o; o.x = f2bf(acc[0] * wd); o.y = f2bf(acc[1] * wd);
        *reinterpret_cast<ushort2*>(m + (size_t)v * NC + lane * 2) = o;
    }
}

// ---------------- MFMA GEMM v9: pure GEMM, NO global atomics ----------------
// v7 (LDS-staged, fused atomic stats) = 63.4us; v8 (direct-global A, fused
// atomic stats) = 68.7us. Duration was K-independent and structure-independent
// -> theory: the ~1.2M device-scope f32 atomicAdds in the fused stats epilogue
// serialize the dispatch. v9: revert to the faster v7 staging structure and
// strip ALL stats/atomics out (moved to deterministic k_stats below).
template <int K>
__global__ __launch_bounds__(256) void k_gemm_mfma(const bf16_t* __restrict__ A,
                                                   const bf16_t* __restrict__ Wt,
                                                   const float* __restrict__ bias,
                                                   bf16_t* __restrict__ C) {
    __shared__ bf16_t lds_raw[64 * (H + 8)];            // 33792 B
    constexpr int LKA = K + 8;                          // padded A-tile row (shorts)
    bf16_t (*aT)[LKA] = reinterpret_cast<bf16_t (*)[LKA]>(lds_raw);
    bf16_t (*cT)[H + 8] = reinterpret_cast<bf16_t (*)[H + 8]>(lds_raw);

    const int tid  = threadIdx.x;
    const int wave = tid >> 6;
    const int lane = tid & 63;
    const int row0 = blockIdx.x * 64;
    const int col0 = wave * 64;
    const int lr = lane & 15;    // fragment row (A) / col (B)
    const int lg = lane >> 4;    // k-group: k = 8*lg .. 8*lg+7

    // ---- stage A tile (64 rows x K, contiguous in global) into padded LDS ----
    {
        const bf16_t* Ag = A + (size_t)row0 * K;
        constexpr int CHUNKS = 64 * K / 8;              // 16B chunks in tile
        #pragma unroll
        for (int it = 0; it < CHUNKS / 256; ++it) {
            int ci  = it * 256 + tid;
            int row = (ci * 8) / K;
            int col = (ci * 8) % K;
            uint4 v = *reinterpret_cast<const uint4*>(Ag + ci * 8);
            *reinterpret_cast<uint4*>(&aT[row][col]) = v;
        }
    }
    __syncthreads();

    f32x4 acc[4][4] = {};        // [mtile][ntile], each 16x16

    const bf16_t* Bb = Wt + (size_t)(col0 + lr) * K + lg * 8;

    #pragma unroll
    for (int ks = 0; ks < K / 32; ++ks) {
        bf16x8 a[4], b[4];
        #pragma unroll
        for (int mt = 0; mt < 4; ++mt)
            a[mt] = *reinterpret_cast<const bf16x8*>(&aT[mt * 16 + lr][ks * 32 + lg * 8]);
        #pragma unroll
        for (int nt = 0; nt < 4; ++nt)
            b[nt] = *reinterpret_cast<const bf16x8*>(Bb + (size_t)nt * 16 * K + ks * 32);
        #pragma unroll
        for (int mt = 0; mt < 4; ++mt)
            #pragma unroll
            for (int nt = 0; nt < 4; ++nt)
                acc[mt][nt] = __builtin_amdgcn_mfma_f32_16x16x32_bf16(a[mt], b[nt], acc[mt][nt], 0, 0, 0);
    }

    __syncthreads();   // A tile fully consumed; reuse LDS for C staging

    // stage into LDS (C/D layout: col = lane&15, row = (lane>>4)*4 + reg)
    #pragma unroll
    for (int nt = 0; nt < 4; ++nt) {
        int c = col0 + nt * 16 + lr;
        float bs = bias[c];
        #pragma unroll
        for (int mt = 0; mt < 4; ++mt) {
            #pragma unroll
            for (int j = 0; j < 4; ++j)
                cT[mt * 16 + lg * 4 + j][c] = f2bf(acc[mt][nt][j] + bs);
        }
    }
    __syncthreads();

    // coalesced write: 64 rows x 256 cols x 2B; 16B per thread per iter
    #pragma unroll
    for (int it = 0; it < 8; ++it) {
        int i = it * 256 + tid;
        int r = i >> 5;          // 32 x 16B segments per 512B row
        int s = i & 31;
        *reinterpret_cast<uint4*>(C + (size_t)(row0 + r) * H + s * 8) =
            *reinterpret_cast<const uint4*>(&cT[r][s * 8]);
    }
}

// ---------------- per-graph stats, deterministic, ZERO atomics ----------------
// One block per graph (bid sorted -> contiguous row range from gstart).
// 512 threads = 8 row-groups x 64 lanes; lane owns a column quad (ushort4).
// Fully coalesced: each 64-lane wave reads one full 512B row per iteration.
// Overwrites gsum/gsumsq -> no memset needed.
__global__ __launch_bounds__(512) void k_stats(const bf16_t* __restrict__ C,
                                               const int* __restrict__ gstart,
                                               float* __restrict__ gsum,
                                               float* __restrict__ gsumsq) {
    __shared__ float red[8][64][9];   // padded to kill bank conflicts
    int b   = blockIdx.x;
    int t   = threadIdx.x;
    int grp = t >> 6;        // 0..7 row-interleave group
    int ln  = t & 63;        // column quad: cols 4*ln .. 4*ln+3
    int n0 = gstart[b], n1 = gstart[b + 1];
    float s[4] = {}, q[4] = {};
    for (int n = n0 + grp; n < n1; n += 8) {
        ushort4 v = *reinterpret_cast<const ushort4*>(C + (size_t)n * H + ln * 4);
        float x0 = bf2f(v.x), x1 = bf2f(v.y), x2 = bf2f(v.z), x3 = bf2f(v.w);
        s[0] += x0; q[0] += x0 * x0;
        s[1] += x1; q[1] += x1 * x1;
        s[2] += x2; q[2] += x2 * x2;
        s[3] += x3; q[3] += x3 * x3;
    }
    #pragma unroll
    for (int j = 0; j < 4; ++j) { red[grp][ln][j] = s[j]; red[grp][ln][4 + j] = q[j]; }
    __syncthreads();
    if (grp == 0) {
        #pragma unroll
        for (int g = 1; g < 8; ++g)
            #pragma unroll
            for (int j = 0; j < 4; ++j) { s[j] += red[g][ln][j]; q[j] += red[g][ln][4 + j]; }
        float4 s4 = { s[0], s[1], s[2], s[3] };
        float4 q4 = { q[0], q[1], q[2], q[3] };
        reinterpret_cast<float4*>(gsum   + (size_t)b * H)[ln] = s4;
        reinterpret_cast<float4*>(gsumsq + (size_t)b * H)[ln] = q4;
    }
}

// ---------------- fused scale/shift + normalize + relu (+ residual) ----------------
template <bool RES>
__global__ void k_norm(const bf16_t* __restrict__ y, const bf16_t* __restrict__ resid,
                       const int* __restrict__ bid, const float* __restrict__ gsum,
                       const float* __restrict__ gsumsq, const float* __restrict__ countsf,
                       const float* __restrict__ gamma, const float* __restrict__ beta,
                       const float* __restrict__ msc, bf16_t* __restrict__ outp) {
    int idx = blockIdx.x * blockDim.x + threadIdx.x;  // over N*H/4
    if (idx >= N_NODES * (H / 4)) return;
    int n  = idx >> 6;      // 64 x ushort4 per row
    int f4 = idx & 63;
    int b  = bid[n];
    float rc = 1.0f / countsf[b];
    float4 s4  = reinterpret_cast<const float4*>(gsum)[b * 64 + f4];
    float4 q4  = reinterpret_cast<const float4*>(gsumsq)[b * 64 + f4];
    float4 g4  = reinterpret_cast<const float4*>(gamma)[f4];
    float4 be4 = reinterpret_cast<const float4*>(beta)[f4];
    float4 m4  = reinterpret_cast<const float4*>(msc)[f4];
    ushort4 yv = reinterpret_cast<const ushort4*>(y)[idx];

    auto nrm = [&](float s, float q, float ga, float be, float m, float yy) {
        float mean = s * rc, ex2 = q * rc;
        float mm   = mean * m;
        float var  = ex2 - 2.f * mean * mm + mm * mm;
        float a    = ga * rsqrtf(var + EPSV);
        return fmaxf(yy * a + (be - a * mm), 0.f);
    };
    float o0 = nrm(s4.x, q4.x, g4.x, be4.x, m4.x, bf2f(yv.x));
    float o1 = nrm(s4.y, q4.y, g4.y, be4.y, m4.y, bf2f(yv.y));
    float o2 = nrm(s4.z, q4.z, g4.z, be4.z, m4.z, bf2f(yv.z));
    float o3 = nrm(s4.w, q4.w, g4.w, be4.w, m4.w, bf2f(yv.w));
    if constexpr (RES) {
        ushort4 r = reinterpret_cast<const ushort4*>(resid)[idx];
        o0 += bf2f(r.x); o1 += bf2f(r.y); o2 += bf2f(r.z); o3 += bf2f(r.w);
    }
    ushort4 o;
    o.x = f2bf(o0); o.y = f2bf(o1); o.z = f2bf(o2); o.w = f2bf(o3);
    reinterpret_cast<ushort4*>(outp)[idx] = o;
}

// ---------------- pooling (sliced, 2-stage) + prediction head ----------------
__global__ void k_pool(const bf16_t* __restrict__ hf, const int* __restrict__ gstart,
                       float* pooled) {
    int b = blockIdx.x, sl = blockIdx.y, f = threadIdx.x;
    int n0 = gstart[b], n1 = gstart[b + 1];
    int cnt = n1 - n0;
    int lo = n0 + (int)((long long)cnt * sl / PSLICES);
    int hi = n0 + (int)((long long)cnt * (sl + 1) / PSLICES);
    if (lo >= hi) return;
    float s = 0.f;
    for (int n = lo; n < hi; ++n) s += bf2f(hf[(size_t)n * H + f]);
    atomicAdd(&pooled[b * H + f], s);
}

__global__ void k_pred(const float* __restrict__ pooled, const float* __restrict__ Wp,
                       const float* __restrict__ bp, float* __restrict__ outp) {
    __shared__ float row[H];
    int b = blockIdx.x;
    row[threadIdx.x] = pooled[b * H + threadIdx.x];
    __syncthreads();
    if (threadIdx.x < OUT_DIM) {
        float acc = bp[threadIdx.x];
        for (int f = 0; f < H; ++f) acc += row[f] * Wp[f * OUT_DIM + threadIdx.x];
        outp[b * OUT_DIM + threadIdx.x] = acc;
    }
}

extern "C" void kernel_launch(void* const* d_in, const int* in_sizes, int n_in,
                              void* d_out, int out_size, void* d_ws, size_t ws_size,
                              hipStream_t stream) {
    const float* h_in  = (const float*)d_in[0];
    const int*   src   = (const int*)d_in[1];
    const int*   dst   = (const int*)d_in[2];
    const int*   bid   = (const int*)d_in[3];
    const float* Wf    = (const float*)d_in[4];
    const float* bfv   = (const float*)d_in[5];
    const float* Wr    = (const float*)d_in[6];
    const float* br    = (const float*)d_in[7];
    const float* gamma = (const float*)d_in[8];
    const float* beta  = (const float*)d_in[9];
    const float* ms    = (const float*)d_in[10];
    const float* Wp    = (const float*)d_in[11];
    const float* bp    = (const float*)d_in[12];
    float* outp = (float*)d_out;

    char* w = (char*)d_ws;
    size_t off = 0;
    auto alloc = [&](size_t bytes) -> void* {
        void* p = w + off;
        off = (off + bytes + 255) & ~(size_t)255;
        return p;
    };
    bf16_t* bufA = (bf16_t*)alloc((size_t)N_PAD * H * 2);
    bf16_t* bufB = (bf16_t*)alloc((size_t)N_PAD * H * 2);
    bf16_t* bufC = (bf16_t*)alloc((size_t)N_PAD * H * 2);
    bf16_t* Wt0  = (bf16_t*)alloc((size_t)H * DIN * 2);
    bf16_t* Wt123= (bf16_t*)alloc((size_t)3 * H * H * 2);
    int* deg_out_i = (int*)alloc(N_NODES * 4);
    int* deg_in_i  = (int*)alloc(N_NODES * 4);
    float* dinv_src = (float*)alloc(N_NODES * 4);
    float* dinv_dst = (float*)alloc(N_NODES * 4);
    int* incl_tmp  = (int*)alloc(N_NODES * 4);
    int* bsums     = (int*)alloc(512 * 4);
    int* boffs     = (int*)alloc(512 * 4);
    int* row_start = (int*)alloc((N_NODES + 1) * 4);
    int* cursor    = (int*)alloc(N_NODES * 4);
    int* csr_src   = (int*)alloc(N_EDGES * 4);
    int* gstart    = (int*)alloc((NB + 1) * 4);
    float* countsf = (float*)alloc(NB * 4);
    float* gsum    = (float*)alloc((size_t)NB * H * 4);
    float* gsumsq  = (float*)alloc((size_t)NB * H * 4);
    float* pooled  = (float*)alloc(NB * H * 4);

    if (off > ws_size) return;   // clean failure instead of OOB

    // hs (prescaled layer-0 input, [N][128] bf16) lives in bufB: it is fully
    // consumed by k_agg before k_gemm_mfma overwrites bufB.
    bf16_t* hs = bufB;

    const int nscan = (N_NODES + SCAN_B - 1) / SCAN_B;

    hipMemsetAsync(deg_out_i, 0, N_NODES * 4, stream);
    hipMemsetAsync(deg_in_i, 0, N_NODES * 4, stream);
    hipMemsetAsync(pooled, 0, NB * H * 4, stream);

    k_edge_deg<<<(N_EDGES + 255) / 256, 256, 0, stream>>>(src, dst, deg_out_i, deg_in_i);
    k_gstart<<<1, 256, 0, stream>>>(bid, gstart, countsf);
    k_dinv<<<(N_NODES + 255) / 256, 256, 0, stream>>>(deg_out_i, deg_in_i, dinv_src, dinv_dst);
    k_scan1<<<nscan, SCAN_B, 0, stream>>>(deg_in_i, incl_tmp, bsums);
    k_scan2<<<1, 512, 0, stream>>>(bsums, boffs, nscan);
    k_scan3<<<(N_NODES + 255) / 256, 256, 0, stream>>>(deg_in_i, incl_tmp, boffs, row_start, cursor);
    k_scatter<<<(N_EDGES + 255) / 256, 256, 0, stream>>>(src, dst, cursor, csr_src);
    k_wt_first<<<(H * DIN + 255) / 256, 256, 0, stream>>>(Wf, Wt0);
    k_wt_rest<<<(3 * H * H + 255) / 256, 256, 0, stream>>>(Wr, Wt123);

    const int aggGrid  = (N_NODES + 3) / 4;
    const int normGrid = (N_NODES * (H / 4) + 255) / 256;
    const int gemmGrid = N_PAD / 64;   // 1564

    // ---- layer 0 ----
    k_prescale<<<(N_NODES * (DIN / 4) + 255) / 256, 256, 0, stream>>>(h_in, dinv_src, hs);
    k_agg<DIN, true><<<aggGrid, 256, 0, stream>>>(hs, nullptr, dinv_dst, row_start, csr_src, bufA);
    k_gemm_mfma<DIN><<<gemmGrid, 256, 0, stream>>>(bufA, Wt0, bfv, bufB);
    k_stats<<<NB, 512, 0, stream>>>(bufB, gstart, gsum, gsumsq);
    k_norm<false><<<normGrid, 256, 0, stream>>>(bufB, nullptr, bid, gsum, gsumsq, countsf,
                                                gamma, beta, ms, bufC);

    // ---- layers 1..3 ----
    bf16_t* hx = bufC;
    bf16_t* f1 = bufA;
    bf16_t* f2 = bufB;
    for (int i = 1; i < 4; ++i) {
        k_agg<H, false><<<aggGrid, 256, 0, stream>>>(hx, dinv_src, dinv_dst, row_start, csr_src, f1);
        k_gemm_mfma<H><<<gemmGrid, 256, 0, stream>>>(f1, Wt123 + (size_t)(i - 1) * H * H,
                                                     br + (i - 1) * H, f2);
        k_stats<<<NB, 512, 0, stream>>>(f2, gstart, gsum, gsumsq);
        k_norm<true><<<normGrid, 256, 0, stream>>>(f2, hx, bid, gsum, gsumsq, countsf,
                                                   gamma + i * H, beta + i * H, ms + i * H, f1);
        bf16_t* nh = f1; f1 = hx; hx = nh;
    }

    k_pool<<<dim3(NB, PSLICES), H, 0, stream>>>(hx, gstart, pooled);
    k_pred<<<NB, H, 0, stream>>>(pooled, Wp, bp, outp);
}

// Round 3
// 656.372 us; speedup vs baseline: 1.0224x; 1.0224x over previous
//
#include <hip/hip_runtime.h>

#define N_NODES 100000
#define N_PAD   100096   // multiple of 64 for GEMM block tiles
#define N_EDGES 320000
#define NB      128
#define DIN     128
#define H       256
#define OUT_DIM 10
#define EPSV    1e-6f
#define SCAN_B  256
#define PSLICES 32
#define NBLK    (N_PAD / 64)   // 1564 GEMM row-blocks

typedef unsigned short bf16_t;
typedef __attribute__((ext_vector_type(8))) short bf16x8;
typedef __attribute__((ext_vector_type(4))) float f32x4;

__device__ __forceinline__ float bf2f(bf16_t u) {
    union { unsigned int i; float f; } x;
    x.i = ((unsigned int)u) << 16;
    return x.f;
}
__device__ __forceinline__ bf16_t f2bf(float f) {
    union { float f; unsigned int i; } x;
    x.f = f;
    unsigned int r = x.i + 0x7fffu + ((x.i >> 16) & 1u);   // round-to-nearest-even
    return (bf16_t)(r >> 16);
}

// ---------------- degree ----------------
__global__ void k_edge_deg(const int* __restrict__ src, const int* __restrict__ dst,
                           int* deg_out, int* deg_in) {
    int e = blockIdx.x * blockDim.x + threadIdx.x;
    if (e < N_EDGES) {
        atomicAdd(&deg_out[src[e]], 1);
        atomicAdd(&deg_in[dst[e]], 1);
    }
}

__global__ void k_dinv(const int* __restrict__ deg_out, const int* __restrict__ deg_in,
                       float* dinv_src, float* dinv_dst) {
    int n = blockIdx.x * blockDim.x + threadIdx.x;
    if (n < N_NODES) {
        dinv_src[n] = rsqrtf((float)max(deg_out[n], 1));
        dinv_dst[n] = rsqrtf((float)max(deg_in[n], 1));
    }
}

// ---------------- graph offsets via binary search (bid is sorted) ----------------
__global__ void k_gstart(const int* __restrict__ bid, int* __restrict__ gstart,
                         float* __restrict__ countsf) {
    int b = threadIdx.x;
    if (b <= NB) {
        int lo = 0, hi = N_NODES;
        while (lo < hi) {
            int mid = (lo + hi) >> 1;
            if (bid[mid] < b) lo = mid + 1; else hi = mid;
        }
        gstart[b] = lo;
    }
    __syncthreads();
    if (b < NB) countsf[b] = (float)max(gstart[b + 1] - gstart[b], 1);
}

// ---------------- hierarchical scan for CSR row_start ----------------
__global__ void k_scan1(const int* __restrict__ deg, int* incl, int* bsums) {
    __shared__ int s[SCAN_B];
    int i = blockIdx.x * SCAN_B + threadIdx.x;
    int v = (i < N_NODES) ? deg[i] : 0;
    s[threadIdx.x] = v;
    __syncthreads();
    for (int d = 1; d < SCAN_B; d <<= 1) {
        int t = (threadIdx.x >= d) ? s[threadIdx.x - d] : 0;
        __syncthreads();
        s[threadIdx.x] += t;
        __syncthreads();
    }
    if (i < N_NODES) incl[i] = s[threadIdx.x];
    if (threadIdx.x == SCAN_B - 1) bsums[blockIdx.x] = s[threadIdx.x];
}

__global__ void k_scan2(const int* __restrict__ bsums, int* boffs, int nb) {
    __shared__ int s[512];
    int t = threadIdx.x;
    int v = (t < nb) ? bsums[t] : 0;
    s[t] = v;
    __syncthreads();
    for (int d = 1; d < 512; d <<= 1) {
        int x = (t >= d) ? s[t - d] : 0;
        __syncthreads();
        s[t] += x;
        __syncthreads();
    }
    if (t < nb) boffs[t] = s[t] - v;   // exclusive
}

__global__ void k_scan3(const int* __restrict__ deg, const int* __restrict__ incl,
                        const int* __restrict__ boffs, int* row_start, int* cursor) {
    int i = blockIdx.x * blockDim.x + threadIdx.x;
    if (i < N_NODES) {
        int ex = incl[i] - deg[i] + boffs[i / SCAN_B];
        row_start[i] = ex;
        cursor[i]    = ex;
    }
    if (i == 0) row_start[N_NODES] = N_EDGES;
}

__global__ void k_scatter(const int* __restrict__ src, const int* __restrict__ dst,
                          int* cursor, int* csr_src) {
    int e = blockIdx.x * blockDim.x + threadIdx.x;
    if (e < N_EDGES) {
        int slot = atomicAdd(&cursor[dst[e]], 1);
        csr_src[slot] = src[e];
    }
}

// ---------------- weight convert + transpose: Wt[c][k] = bf16(W[k][c]) ----------------
__global__ void k_wt_first(const float* __restrict__ W, bf16_t* __restrict__ Wt) {
    int idx = blockIdx.x * 256 + threadIdx.x;   // idx = c*DIN + k
    if (idx >= H * DIN) return;
    int c = idx / DIN, k = idx % DIN;
    Wt[idx] = f2bf(W[k * H + c]);
}
__global__ void k_wt_rest(const float* __restrict__ W, bf16_t* __restrict__ Wt) {
    int idx = blockIdx.x * 256 + threadIdx.x;   // idx = l*H*H + c*H + k
    if (idx >= 3 * H * H) return;
    int l = idx / (H * H);
    int rem = idx % (H * H);
    int c = rem / H, k = rem % H;
    Wt[idx] = f2bf(W[(size_t)l * H * H + k * H + c]);
}

// ---------------- layer-0 prescale: hs[n][c] = bf16(h[n][c] * dinv_src[n]) ----------------
__global__ void k_prescale(const float* __restrict__ h, const float* __restrict__ dinv_s,
                           bf16_t* __restrict__ hs) {
    int idx = blockIdx.x * blockDim.x + threadIdx.x;   // over N * DIN/4
    if (idx >= N_NODES * (DIN / 4)) return;
    int n = idx >> 5;                                  // DIN/4 = 32
    float w = dinv_s[n];
    float4 v = reinterpret_cast<const float4*>(h)[idx];
    ushort4 o;
    o.x = f2bf(v.x * w); o.y = f2bf(v.y * w);
    o.z = f2bf(v.z * w); o.w = f2bf(v.w * w);
    reinterpret_cast<ushort4*>(hs)[idx] = o;
}

// ---------------- aggregation: one wave per node, CSR by dst ----------------
template <int NC, bool PS>
__global__ void k_agg(const bf16_t* __restrict__ hx, const float* __restrict__ dinv_s,
                      const float* __restrict__ dinv_d, const int* __restrict__ row_start,
                      const int* __restrict__ csr_src, bf16_t* __restrict__ m) {
    constexpr int VEC = NC / 64;     // ushorts per lane (2 or 4)
    int gid  = blockIdx.x * blockDim.x + threadIdx.x;
    int v    = gid >> 6;
    int lane = gid & 63;
    if (v >= N_NODES) return;
    float acc[VEC] = {};
    int s0 = row_start[v], s1 = row_start[v + 1];

    auto body = [&](int ei) {
        int si = csr_src[ei];
        float wv = 1.f;
        if constexpr (!PS) wv = dinv_s[si];
        if constexpr (VEC == 4) {
            ushort4 r = *reinterpret_cast<const ushort4*>(hx + (size_t)si * NC + lane * 4);
            acc[0] += bf2f(r.x) * wv; acc[1] += bf2f(r.y) * wv;
            acc[2] += bf2f(r.z) * wv; acc[3] += bf2f(r.w) * wv;
        } else {
            ushort2 r = *reinterpret_cast<const ushort2*>(hx + (size_t)si * NC + lane * 2);
            acc[0] += bf2f(r.x) * wv; acc[1] += bf2f(r.y) * wv;
        }
    };

    int e = s0;
    for (; e + 3 < s1; e += 4) { body(e); body(e + 1); body(e + 2); body(e + 3); }
    for (; e < s1; ++e) body(e);

    float wd = dinv_d[v];
    if constexpr (VEC == 4) {
        ushort4 o;
        o.x = f2bf(acc[0] * wd); o.y = f2bf(acc[1] * wd);
        o.z = f2bf(acc[2] * wd); o.w = f2bf(acc[3] * wd);
        *reinterpret_cast<ushort4*>(m + (size_t)v * NC + lane * 4) = o;
    } else {
        ushort2 o; o.x = f2bf(acc[0] * wd); o.y = f2bf(acc[1] * wd);
        *reinterpret_cast<ushort2*>(m + (size_t)v * NC + lane * 2) = o;
    }
}

// ---------------- MFMA GEMM v10: pure GEMM + deterministic per-block stats ----------------
// v9 (no stats) = 45us proved the fused f32 atomics were the v7/v8 serializer;
// but the separate k_stats pass (128 blocks = half-idle GPU) cost 30us/layer.
// v10: epilogue walks the 64 staged C rows per column and writes per-block
// (sum,sumsq) partials split by relative graph id (a 64-row block spans <=2
// graphs since graphs are ~780 rows; 3 planes for safety). Zero atomics, fully
// coalesced float2 writes; a tiny k_stats_red folds partials per graph.
template <int K>
__global__ __launch_bounds__(256) void k_gemm_mfma(const bf16_t* __restrict__ A,
                                                   const bf16_t* __restrict__ Wt,
                                                   const float* __restrict__ bias,
                                                   const int* __restrict__ bid,
                                                   bf16_t* __restrict__ C,
                                                   float2* __restrict__ part) {
    __shared__ bf16_t lds_raw[64 * (H + 8)];            // 33792 B
    __shared__ int bid_lds[64];
    constexpr int LKA = K + 8;                          // padded A-tile row (shorts)
    bf16_t (*aT)[LKA] = reinterpret_cast<bf16_t (*)[LKA]>(lds_raw);
    bf16_t (*cT)[H + 8] = reinterpret_cast<bf16_t (*)[H + 8]>(lds_raw);

    const int tid  = threadIdx.x;
    const int wave = tid >> 6;
    const int lane = tid & 63;
    const int row0 = blockIdx.x * 64;
    const int col0 = wave * 64;
    const int lr = lane & 15;    // fragment row (A) / col (B)
    const int lg = lane >> 4;    // k-group: k = 8*lg .. 8*lg+7

    // ---- stage A tile (64 rows x K, contiguous in global) into padded LDS ----
    {
        const bf16_t* Ag = A + (size_t)row0 * K;
        constexpr int CHUNKS = 64 * K / 8;              // 16B chunks in tile
        #pragma unroll
        for (int it = 0; it < CHUNKS / 256; ++it) {
            int ci  = it * 256 + tid;
            int row = (ci * 8) / K;
            int col = (ci * 8) % K;
            uint4 v = *reinterpret_cast<const uint4*>(Ag + ci * 8);
            *reinterpret_cast<uint4*>(&aT[row][col]) = v;
        }
    }
    if (tid < 64) {
        int r = row0 + tid;
        bid_lds[tid] = (r < N_NODES) ? bid[r] : -1;
    }
    __syncthreads();

    f32x4 acc[4][4] = {};        // [mtile][ntile], each 16x16

    const bf16_t* Bb = Wt + (size_t)(col0 + lr) * K + lg * 8;

    #pragma unroll
    for (int ks = 0; ks < K / 32; ++ks) {
        bf16x8 a[4], b[4];
        #pragma unroll
        for (int mt = 0; mt < 4; ++mt)
            a[mt] = *reinterpret_cast<const bf16x8*>(&aT[mt * 16 + lr][ks * 32 + lg * 8]);
        #pragma unroll
        for (int nt = 0; nt < 4; ++nt)
            b[nt] = *reinterpret_cast<const bf16x8*>(Bb + (size_t)nt * 16 * K + ks * 32);
        #pragma unroll
        for (int mt = 0; mt < 4; ++mt)
            #pragma unroll
            for (int nt = 0; nt < 4; ++nt)
                acc[mt][nt] = __builtin_amdgcn_mfma_f32_16x16x32_bf16(a[mt], b[nt], acc[mt][nt], 0, 0, 0);
    }

    __syncthreads();   // A tile fully consumed; reuse LDS for C staging

    // stage into LDS (C/D layout: col = lane&15, row = (lane>>4)*4 + reg)
    #pragma unroll
    for (int nt = 0; nt < 4; ++nt) {
        int c = col0 + nt * 16 + lr;
        float bs = bias[c];
        #pragma unroll
        for (int mt = 0; mt < 4; ++mt) {
            #pragma unroll
            for (int j = 0; j < 4; ++j)
                cT[mt * 16 + lg * 4 + j][c] = f2bf(acc[mt][nt][j] + bs);
        }
    }
    __syncthreads();

    // coalesced write: 64 rows x 256 cols x 2B; 16B per thread per iter
    #pragma unroll
    for (int it = 0; it < 8; ++it) {
        int i = it * 256 + tid;
        int r = i >> 5;          // 32 x 16B segments per 512B row
        int s = i & 31;
        *reinterpret_cast<uint4*>(C + (size_t)(row0 + r) * H + s * 8) =
            *reinterpret_cast<const uint4*>(&cT[r][s * 8]);
    }

    // ---- per-block stats partials: thread owns column c=tid, zero atomics ----
    {
        const int c = tid;
        float s0 = 0.f, q0 = 0.f, s1 = 0.f, q1 = 0.f, s2 = 0.f, q2 = 0.f;
        const int g0 = bid_lds[0];
        for (int r = 0; r < 64; ++r) {
            int g = bid_lds[r];
            if (g < 0) break;                  // pad rows (sorted: only at end)
            float v = bf2f(cT[r][c]);
            int rel = g - g0;
            if (rel == 0)      { s0 += v; q0 += v * v; }
            else if (rel == 1) { s1 += v; q1 += v * v; }
            else if (rel == 2) { s2 += v; q2 += v * v; }
        }
        size_t base = (size_t)blockIdx.x * H + c;
        constexpr size_t PLANE = (size_t)NBLK * H;
        part[0 * PLANE + base] = make_float2(s0, q0);
        part[1 * PLANE + base] = make_float2(s1, q1);
        part[2 * PLANE + base] = make_float2(s2, q2);
    }
}

// ---------------- fold per-block partials into per-graph stats ----------------
// Graph b covers rows [gstart[b], gstart[b+1]) -> blocks n0/64 .. (n1-1)/64
// (~13 blocks). rel plane of block blk for graph b is b - bid[blk*64].
__global__ void k_stats_red(const float2* __restrict__ part, const int* __restrict__ bid,
                            const int* __restrict__ gstart,
                            float* __restrict__ gsum, float* __restrict__ gsumsq) {
    constexpr size_t PLANE = (size_t)NBLK * H;
    int b = blockIdx.x;
    int c = threadIdx.x;
    int n0 = gstart[b], n1 = gstart[b + 1];
    float s = 0.f, q = 0.f;
    if (n1 > n0) {
        int blo = n0 >> 6, bhi = (n1 - 1) >> 6;
        for (int blk = blo; blk <= bhi; ++blk) {
            int rel = b - bid[blk << 6];
            if (rel >= 0 && rel < 3) {
                float2 v = part[(size_t)rel * PLANE + (size_t)blk * H + c];
                s += v.x; q += v.y;
            }
        }
    }
    gsum[b * H + c]   = s;
    gsumsq[b * H + c] = q;
}

// ---------------- fused scale/shift + normalize + relu (+ residual) ----------------
template <bool RES>
__global__ void k_norm(const bf16_t* __restrict__ y, const bf16_t* __restrict__ resid,
                       const int* __restrict__ bid, const float* __restrict__ gsum,
                       const float* __restrict__ gsumsq, const float* __restrict__ countsf,
                       const float* __restrict__ gamma, const float* __restrict__ beta,
                       const float* __restrict__ msc, bf16_t* __restrict__ outp) {
    int idx = blockIdx.x * blockDim.x + threadIdx.x;  // over N*H/4
    if (idx >= N_NODES * (H / 4)) return;
    int n  = idx >> 6;      // 64 x ushort4 per row
    int f4 = idx & 63;
    int b  = bid[n];
    float rc = 1.0f / countsf[b];
    float4 s4  = reinterpret_cast<const float4*>(gsum)[b * 64 + f4];
    float4 q4  = reinterpret_cast<const float4*>(gsumsq)[b * 64 + f4];
    float4 g4  = reinterpret_cast<const float4*>(gamma)[f4];
    float4 be4 = reinterpret_cast<const float4*>(beta)[f4];
    float4 m4  = reinterpret_cast<const float4*>(msc)[f4];
    ushort4 yv = reinterpret_cast<const ushort4*>(y)[idx];

    auto nrm = [&](float s, float q, float ga, float be, float m, float yy) {
        float mean = s * rc, ex2 = q * rc;
        float mm   = mean * m;
        float var  = ex2 - 2.f * mean * mm + mm * mm;
        float a    = ga * rsqrtf(var + EPSV);
        return fmaxf(yy * a + (be - a * mm), 0.f);
    };
    float o0 = nrm(s4.x, q4.x, g4.x, be4.x, m4.x, bf2f(yv.x));
    float o1 = nrm(s4.y, q4.y, g4.y, be4.y, m4.y, bf2f(yv.y));
    float o2 = nrm(s4.z, q4.z, g4.z, be4.z, m4.z, bf2f(yv.z));
    float o3 = nrm(s4.w, q4.w, g4.w, be4.w, m4.w, bf2f(yv.w));
    if constexpr (RES) {
        ushort4 r = reinterpret_cast<const ushort4*>(resid)[idx];
        o0 += bf2f(r.x); o1 += bf2f(r.y); o2 += bf2f(r.z); o3 += bf2f(r.w);
    }
    ushort4 o;
    o.x = f2bf(o0); o.y = f2bf(o1); o.z = f2bf(o2); o.w = f2bf(o3);
    reinterpret_cast<ushort4*>(outp)[idx] = o;
}

// ---------------- pooling (sliced, 2-stage) + prediction head ----------------
__global__ void k_pool(const bf16_t* __restrict__ hf, const int* __restrict__ gstart,
                       float* pooled) {
    int b = blockIdx.x, sl = blockIdx.y, f = threadIdx.x;
    int n0 = gstart[b], n1 = gstart[b + 1];
    int cnt = n1 - n0;
    int lo = n0 + (int)((long long)cnt * sl / PSLICES);
    int hi = n0 + (int)((long long)cnt * (sl + 1) / PSLICES);
    if (lo >= hi) return;
    float s = 0.f;
    for (int n = lo; n < hi; ++n) s += bf2f(hf[(size_t)n * H + f]);
    atomicAdd(&pooled[b * H + f], s);
}

__global__ void k_pred(const float* __restrict__ pooled, const float* __restrict__ Wp,
                       const float* __restrict__ bp, float* __restrict__ outp) {
    __shared__ float row[H];
    int b = blockIdx.x;
    row[threadIdx.x] = pooled[b * H + threadIdx.x];
    __syncthreads();
    if (threadIdx.x < OUT_DIM) {
        float acc = bp[threadIdx.x];
        for (int f = 0; f < H; ++f) acc += row[f] * Wp[f * OUT_DIM + threadIdx.x];
        outp[b * OUT_DIM + threadIdx.x] = acc;
    }
}

extern "C" void kernel_launch(void* const* d_in, const int* in_sizes, int n_in,
                              void* d_out, int out_size, void* d_ws, size_t ws_size,
                              hipStream_t stream) {
    const float* h_in  = (const float*)d_in[0];
    const int*   src   = (const int*)d_in[1];
    const int*   dst   = (const int*)d_in[2];
    const int*   bid   = (const int*)d_in[3];
    const float* Wf    = (const float*)d_in[4];
    const float* bfv   = (const float*)d_in[5];
    const float* Wr    = (const float*)d_in[6];
    const float* br    = (const float*)d_in[7];
    const float* gamma = (const float*)d_in[8];
    const float* beta  = (const float*)d_in[9];
    const float* ms    = (const float*)d_in[10];
    const float* Wp    = (const float*)d_in[11];
    const float* bp    = (const float*)d_in[12];
    float* outp = (float*)d_out;

    char* w = (char*)d_ws;
    size_t off = 0;
    auto alloc = [&](size_t bytes) -> void* {
        void* p = w + off;
        off = (off + bytes + 255) & ~(size_t)255;
        return p;
    };
    bf16_t* bufA = (bf16_t*)alloc((size_t)N_PAD * H * 2);
    bf16_t* bufB = (bf16_t*)alloc((size_t)N_PAD * H * 2);
    bf16_t* bufC = (bf16_t*)alloc((size_t)N_PAD * H * 2);
    bf16_t* Wt0  = (bf16_t*)alloc((size_t)H * DIN * 2);
    bf16_t* Wt123= (bf16_t*)alloc((size_t)3 * H * H * 2);
    int* deg_out_i = (int*)alloc(N_NODES * 4);
    int* deg_in_i  = (int*)alloc(N_NODES * 4);
    float* dinv_src = (float*)alloc(N_NODES * 4);
    float* dinv_dst = (float*)alloc(N_NODES * 4);
    int* incl_tmp  = (int*)alloc(N_NODES * 4);
    int* bsums     = (int*)alloc(512 * 4);
    int* boffs     = (int*)alloc(512 * 4);
    int* row_start = (int*)alloc((N_NODES + 1) * 4);
    int* cursor    = (int*)alloc(N_NODES * 4);
    int* csr_src   = (int*)alloc(N_EDGES * 4);
    int* gstart    = (int*)alloc((NB + 1) * 4);
    float* countsf = (float*)alloc(NB * 4);
    float* gsum    = (float*)alloc((size_t)NB * H * 4);
    float* gsumsq  = (float*)alloc((size_t)NB * H * 4);
    float2* part   = (float2*)alloc((size_t)3 * NBLK * H * 8);   // 9.6 MB
    float* pooled  = (float*)alloc(NB * H * 4);

    if (off > ws_size) return;   // clean failure instead of OOB

    // hs (prescaled layer-0 input, [N][128] bf16) lives in bufB: it is fully
    // consumed by k_agg before k_gemm_mfma overwrites bufB.
    bf16_t* hs = bufB;

    const int nscan = (N_NODES + SCAN_B - 1) / SCAN_B;

    hipMemsetAsync(deg_out_i, 0, N_NODES * 4, stream);
    hipMemsetAsync(deg_in_i, 0, N_NODES * 4, stream);
    hipMemsetAsync(pooled, 0, NB * H * 4, stream);

    k_edge_deg<<<(N_EDGES + 255) / 256, 256, 0, stream>>>(src, dst, deg_out_i, deg_in_i);
    k_gstart<<<1, 256, 0, stream>>>(bid, gstart, countsf);
    k_dinv<<<(N_NODES + 255) / 256, 256, 0, stream>>>(deg_out_i, deg_in_i, dinv_src, dinv_dst);
    k_scan1<<<nscan, SCAN_B, 0, stream>>>(deg_in_i, incl_tmp, bsums);
    k_scan2<<<1, 512, 0, stream>>>(bsums, boffs, nscan);
    k_scan3<<<(N_NODES + 255) / 256, 256, 0, stream>>>(deg_in_i, incl_tmp, boffs, row_start, cursor);
    k_scatter<<<(N_EDGES + 255) / 256, 256, 0, stream>>>(src, dst, cursor, csr_src);
    k_wt_first<<<(H * DIN + 255) / 256, 256, 0, stream>>>(Wf, Wt0);
    k_wt_rest<<<(3 * H * H + 255) / 256, 256, 0, stream>>>(Wr, Wt123);

    const int aggGrid  = (N_NODES + 3) / 4;
    const int normGrid = (N_NODES * (H / 4) + 255) / 256;
    const int gemmGrid = NBLK;

    // ---- layer 0 ----
    k_prescale<<<(N_NODES * (DIN / 4) + 255) / 256, 256, 0, stream>>>(h_in, dinv_src, hs);
    k_agg<DIN, true><<<aggGrid, 256, 0, stream>>>(hs, nullptr, dinv_dst, row_start, csr_src, bufA);
    k_gemm_mfma<DIN><<<gemmGrid, 256, 0, stream>>>(bufA, Wt0, bfv, bid, bufB, part);
    k_stats_red<<<NB, H, 0, stream>>>(part, bid, gstart, gsum, gsumsq);
    k_norm<false><<<normGrid, 256, 0, stream>>>(bufB, nullptr, bid, gsum, gsumsq, countsf,
                                                gamma, beta, ms, bufC);

    // ---- layers 1..3 ----
    bf16_t* hx = bufC;
    bf16_t* f1 = bufA;
    bf16_t* f2 = bufB;
    for (int i = 1; i < 4; ++i) {
        k_agg<H, false><<<aggGrid, 256, 0, stream>>>(hx, dinv_src, dinv_dst, row_start, csr_src, f1);
        k_gemm_mfma<H><<<gemmGrid, 256, 0, stream>>>(f1, Wt123 + (size_t)(i - 1) * H * H,
                                                     br + (i - 1) * H, bid, f2, part);
        k_stats_red<<<NB, H, 0, stream>>>(part, bid, gstart, gsum, gsumsq);
        k_norm<true><<<normGrid, 256, 0, stream>>>(f2, hx, bid, gsum, gsumsq, countsf,
                                                   gamma + i * H, beta + i * H, ms + i * H, f1);
        bf16_t* nh = f1; f1 = hx; hx = nh;
    }

    k_pool<<<dim3(NB, PSLICES), H, 0, stream>>>(hx, gstart, pooled);
    k_pred<<<NB, H, 0, stream>>>(pooled, Wp, bp, outp);
}

// Round 4
// 594.282 us; speedup vs baseline: 1.1292x; 1.1045x over previous
//
#include <hip/hip_runtime.h>

#define N_NODES 100000
#define N_PAD   100096   // multiple of 64 for GEMM block tiles
#define N_EDGES 320000
#define NB      128
#define DIN     128
#define H       256
#define OUT_DIM 10
#define EPSV    1e-6f
#define SCAN_B  256
#define PSLICES 32
#define NBLK    (N_PAD / 64)   // 1564 GEMM row-blocks

typedef unsigned short bf16_t;
typedef __attribute__((ext_vector_type(8))) short bf16x8;
typedef __attribute__((ext_vector_type(4))) float f32x4;

__device__ __forceinline__ float bf2f(bf16_t u) {
    union { unsigned int i; float f; } x;
    x.i = ((unsigned int)u) << 16;
    return x.f;
}
__device__ __forceinline__ bf16_t f2bf(float f) {
    union { float f; unsigned int i; } x;
    x.f = f;
    unsigned int r = x.i + 0x7fffu + ((x.i >> 16) & 1u);   // round-to-nearest-even
    return (bf16_t)(r >> 16);
}

// ---------------- degree ----------------
__global__ void k_edge_deg(const int* __restrict__ src, const int* __restrict__ dst,
                           int* deg_out, int* deg_in) {
    int e = blockIdx.x * blockDim.x + threadIdx.x;
    if (e < N_EDGES) {
        atomicAdd(&deg_out[src[e]], 1);
        atomicAdd(&deg_in[dst[e]], 1);
    }
}

__global__ void k_dinv(const int* __restrict__ deg_out, const int* __restrict__ deg_in,
                       float* dinv_src, float* dinv_dst) {
    int n = blockIdx.x * blockDim.x + threadIdx.x;
    if (n < N_NODES) {
        dinv_src[n] = rsqrtf((float)max(deg_out[n], 1));
        dinv_dst[n] = rsqrtf((float)max(deg_in[n], 1));
    }
}

// ---------------- graph offsets via binary search (bid is sorted) ----------------
__global__ void k_gstart(const int* __restrict__ bid, int* __restrict__ gstart,
                         float* __restrict__ countsf) {
    int b = threadIdx.x;
    if (b <= NB) {
        int lo = 0, hi = N_NODES;
        while (lo < hi) {
            int mid = (lo + hi) >> 1;
            if (bid[mid] < b) lo = mid + 1; else hi = mid;
        }
        gstart[b] = lo;
    }
    __syncthreads();
    if (b < NB) countsf[b] = (float)max(gstart[b + 1] - gstart[b], 1);
}

// ---------------- hierarchical scan for CSR row_start ----------------
__global__ void k_scan1(const int* __restrict__ deg, int* incl, int* bsums) {
    __shared__ int s[SCAN_B];
    int i = blockIdx.x * SCAN_B + threadIdx.x;
    int v = (i < N_NODES) ? deg[i] : 0;
    s[threadIdx.x] = v;
    __syncthreads();
    for (int d = 1; d < SCAN_B; d <<= 1) {
        int t = (threadIdx.x >= d) ? s[threadIdx.x - d] : 0;
        __syncthreads();
        s[threadIdx.x] += t;
        __syncthreads();
    }
    if (i < N_NODES) incl[i] = s[threadIdx.x];
    if (threadIdx.x == SCAN_B - 1) bsums[blockIdx.x] = s[threadIdx.x];
}

__global__ void k_scan2(const int* __restrict__ bsums, int* boffs, int nb) {
    __shared__ int s[512];
    int t = threadIdx.x;
    int v = (t < nb) ? bsums[t] : 0;
    s[t] = v;
    __syncthreads();
    for (int d = 1; d < 512; d <<= 1) {
        int x = (t >= d) ? s[t - d] : 0;
        __syncthreads();
        s[t] += x;
        __syncthreads();
    }
    if (t < nb) boffs[t] = s[t] - v;   // exclusive
}

__global__ void k_scan3(const int* __restrict__ deg, const int* __restrict__ incl,
                        const int* __restrict__ boffs, int* row_start, int* cursor) {
    int i = blockIdx.x * blockDim.x + threadIdx.x;
    if (i < N_NODES) {
        int ex = incl[i] - deg[i] + boffs[i / SCAN_B];
        row_start[i] = ex;
        cursor[i]    = ex;
    }
    if (i == 0) row_start[N_NODES] = N_EDGES;
}

__global__ void k_scatter(const int* __restrict__ src, const int* __restrict__ dst,
                          int* cursor, int* csr_src) {
    int e = blockIdx.x * blockDim.x + threadIdx.x;
    if (e < N_EDGES) {
        int slot = atomicAdd(&cursor[dst[e]], 1);
        csr_src[slot] = src[e];
    }
}

// ---------------- weight convert + transpose: Wt[c][k] = bf16(W[k][c]) ----------------
__global__ void k_wt_first(const float* __restrict__ W, bf16_t* __restrict__ Wt) {
    int idx = blockIdx.x * 256 + threadIdx.x;   // idx = c*DIN + k
    if (idx >= H * DIN) return;
    int c = idx / DIN, k = idx % DIN;
    Wt[idx] = f2bf(W[k * H + c]);
}
__global__ void k_wt_rest(const float* __restrict__ W, bf16_t* __restrict__ Wt) {
    int idx = blockIdx.x * 256 + threadIdx.x;   // idx = l*H*H + c*H + k
    if (idx >= 3 * H * H) return;
    int l = idx / (H * H);
    int rem = idx % (H * H);
    int c = rem / H, k = rem % H;
    Wt[idx] = f2bf(W[(size_t)l * H * H + k * H + c]);
}

// ---------------- layer-0 prescale: hs[n][c] = bf16(h[n][c] * dinv_src[n]) ----------------
__global__ void k_prescale(const float* __restrict__ h, const float* __restrict__ dinv_s,
                           bf16_t* __restrict__ hs) {
    int idx = blockIdx.x * blockDim.x + threadIdx.x;   // over N * DIN/4
    if (idx >= N_NODES * (DIN / 4)) return;
    int n = idx >> 5;                                  // DIN/4 = 32
    float w = dinv_s[n];
    float4 v = reinterpret_cast<const float4*>(h)[idx];
    ushort4 o;
    o.x = f2bf(v.x * w); o.y = f2bf(v.y * w);
    o.z = f2bf(v.z * w); o.w = f2bf(v.w * w);
    reinterpret_cast<ushort4*>(hs)[idx] = o;
}

// ---------------- aggregation: one wave per node, CSR by dst ----------------
template <int NC, bool PS>
__global__ void k_agg(const bf16_t* __restrict__ hx, const float* __restrict__ dinv_s,
                      const float* __restrict__ dinv_d, const int* __restrict__ row_start,
                      const int* __restrict__ csr_src, bf16_t* __restrict__ m) {
    constexpr int VEC = NC / 64;     // ushorts per lane (2 or 4)
    int gid  = blockIdx.x * blockDim.x + threadIdx.x;
    int v    = gid >> 6;
    int lane = gid & 63;
    if (v >= N_NODES) return;
    float acc[VEC] = {};
    int s0 = row_start[v], s1 = row_start[v + 1];

    auto body = [&](int ei) {
        int si = csr_src[ei];
        float wv = 1.f;
        if constexpr (!PS) wv = dinv_s[si];
        if constexpr (VEC == 4) {
            ushort4 r = *reinterpret_cast<const ushort4*>(hx + (size_t)si * NC + lane * 4);
            acc[0] += bf2f(r.x) * wv; acc[1] += bf2f(r.y) * wv;
            acc[2] += bf2f(r.z) * wv; acc[3] += bf2f(r.w) * wv;
        } else {
            ushort2 r = *reinterpret_cast<const ushort2*>(hx + (size_t)si * NC + lane * 2);
            acc[0] += bf2f(r.x) * wv; acc[1] += bf2f(r.y) * wv;
        }
    };

    int e = s0;
    for (; e + 3 < s1; e += 4) { body(e); body(e + 1); body(e + 2); body(e + 3); }
    for (; e < s1; ++e) body(e);

    float wd = dinv_d[v];
    if constexpr (VEC == 4) {
        ushort4 o;
        o.x = f2bf(acc[0] * wd); o.y = f2bf(acc[1] * wd);
        o.z = f2bf(acc[2] * wd); o.w = f2bf(acc[3] * wd);
        *reinterpret_cast<ushort4*>(m + (size_t)v * NC + lane * 4) = o;
    } else {
        ushort2 o; o.x = f2bf(acc[0] * wd); o.y = f2bf(acc[1] * wd);
        *reinterpret_cast<ushort2*>(m + (size_t)v * NC + lane * 2) = o;
    }
}

// ---------------- MFMA GEMM v11: stats from ACCUMULATOR REGISTERS ----------------
// Ledger: v9 pure GEMM = 45us; v7 (walk->atomics) = 63; v10 (walk->writes) = 64.5.
// => the 64-iter LDS column-walk (serial dependent ds_reads + early-exit break,
// ~15k unpipelineable cycles/wave) was the cost, NOT the atomics.
// v11: every C value already sits in acc[mt][nt][j]; rows' relative graph ids
// come from a 64-byte rel_lds table. Branch-free masked accumulate into
// s/q[3 rel][4 nt] (~640 VALU), then 2-step shfl_xor reduce across the 4
// k-group lanes, and lanes lg==0 write 12 coalesced float2 partials.
template <int K>
__global__ __launch_bounds__(256) void k_gemm_mfma(const bf16_t* __restrict__ A,
                                                   const bf16_t* __restrict__ Wt,
                                                   const float* __restrict__ bias,
                                                   const int* __restrict__ bid,
                                                   bf16_t* __restrict__ C,
                                                   float2* __restrict__ part) {
    __shared__ bf16_t lds_raw[64 * (H + 8)];            // 33792 B
    __shared__ unsigned char rel_lds[64];
    constexpr int LKA = K + 8;                          // padded A-tile row (shorts)
    bf16_t (*aT)[LKA] = reinterpret_cast<bf16_t (*)[LKA]>(lds_raw);
    bf16_t (*cT)[H + 8] = reinterpret_cast<bf16_t (*)[H + 8]>(lds_raw);

    const int tid  = threadIdx.x;
    const int wave = tid >> 6;
    const int lane = tid & 63;
    const int row0 = blockIdx.x * 64;
    const int col0 = wave * 64;
    const int lr = lane & 15;    // fragment row (A) / col (B)
    const int lg = lane >> 4;    // k-group: k = 8*lg .. 8*lg+7

    // ---- stage A tile (64 rows x K, contiguous in global) into padded LDS ----
    {
        const bf16_t* Ag = A + (size_t)row0 * K;
        constexpr int CHUNKS = 64 * K / 8;              // 16B chunks in tile
        #pragma unroll
        for (int it = 0; it < CHUNKS / 256; ++it) {
            int ci  = it * 256 + tid;
            int row = (ci * 8) / K;
            int col = (ci * 8) % K;
            uint4 v = *reinterpret_cast<const uint4*>(Ag + ci * 8);
            *reinterpret_cast<uint4*>(&aT[row][col]) = v;
        }
    }
    if (tid < 64) {
        int r  = row0 + tid;
        int g0 = bid[(row0 < N_NODES) ? row0 : (N_NODES - 1)];
        rel_lds[tid] = (r < N_NODES) ? (unsigned char)(bid[r] - g0)
                                     : (unsigned char)255;
    }
    __syncthreads();

    f32x4 acc[4][4] = {};        // [mtile][ntile], each 16x16

    const bf16_t* Bb = Wt + (size_t)(col0 + lr) * K + lg * 8;

    #pragma unroll
    for (int ks = 0; ks < K / 32; ++ks) {
        bf16x8 a[4], b[4];
        #pragma unroll
        for (int mt = 0; mt < 4; ++mt)
            a[mt] = *reinterpret_cast<const bf16x8*>(&aT[mt * 16 + lr][ks * 32 + lg * 8]);
        #pragma unroll
        for (int nt = 0; nt < 4; ++nt)
            b[nt] = *reinterpret_cast<const bf16x8*>(Bb + (size_t)nt * 16 * K + ks * 32);
        #pragma unroll
        for (int mt = 0; mt < 4; ++mt)
            #pragma unroll
            for (int nt = 0; nt < 4; ++nt)
                acc[mt][nt] = __builtin_amdgcn_mfma_f32_16x16x32_bf16(a[mt], b[nt], acc[mt][nt], 0, 0, 0);
    }

    // ---- biases (used by both stats and C staging) ----
    float bsn[4];
    #pragma unroll
    for (int nt = 0; nt < 4; ++nt) bsn[nt] = bias[col0 + nt * 16 + lr];

    // ---- stats from accumulators: branch-free masked accumulate ----
    {
        unsigned int relw[4];
        #pragma unroll
        for (int mt = 0; mt < 4; ++mt)
            relw[mt] = *reinterpret_cast<const unsigned int*>(&rel_lds[mt * 16 + lg * 4]);

        float sA[3][4] = {}, qA[3][4] = {};
        #pragma unroll
        for (int mt = 0; mt < 4; ++mt) {
            #pragma unroll
            for (int j = 0; j < 4; ++j) {
                int rv = (relw[mt] >> (8 * j)) & 0xff;
                #pragma unroll
                for (int nt = 0; nt < 4; ++nt) {
                    float v  = acc[mt][nt][j] + bsn[nt];
                    float v0 = (rv == 0) ? v : 0.f;
                    float v1 = (rv == 1) ? v : 0.f;
                    float v2 = (rv == 2) ? v : 0.f;
                    sA[0][nt] += v0; qA[0][nt] += v0 * v0;
                    sA[1][nt] += v1; qA[1][nt] += v1 * v1;
                    sA[2][nt] += v2; qA[2][nt] += v2 * v2;
                }
            }
        }
        // reduce across the 4 k-group lanes (lane ^16, ^32)
        #pragma unroll
        for (int rel = 0; rel < 3; ++rel) {
            #pragma unroll
            for (int nt = 0; nt < 4; ++nt) {
                float sv = sA[rel][nt], qv = qA[rel][nt];
                sv += __shfl_xor(sv, 16); qv += __shfl_xor(qv, 16);
                sv += __shfl_xor(sv, 32); qv += __shfl_xor(qv, 32);
                sA[rel][nt] = sv; qA[rel][nt] = qv;
            }
        }
        if (lg == 0) {
            constexpr size_t PLANE = (size_t)NBLK * H;
            #pragma unroll
            for (int rel = 0; rel < 3; ++rel)
                #pragma unroll
                for (int nt = 0; nt < 4; ++nt)
                    part[(size_t)rel * PLANE + (size_t)blockIdx.x * H + col0 + nt * 16 + lr]
                        = make_float2(sA[rel][nt], qA[rel][nt]);
        }
    }

    __syncthreads();   // A tile fully consumed; reuse LDS for C staging

    // stage into LDS (C/D layout: col = lane&15, row = (lane>>4)*4 + reg)
    #pragma unroll
    for (int nt = 0; nt < 4; ++nt) {
        int c = col0 + nt * 16 + lr;
        #pragma unroll
        for (int mt = 0; mt < 4; ++mt) {
            #pragma unroll
            for (int j = 0; j < 4; ++j)
                cT[mt * 16 + lg * 4 + j][c] = f2bf(acc[mt][nt][j] + bsn[nt]);
        }
    }
    __syncthreads();

    // coalesced write: 64 rows x 256 cols x 2B; 16B per thread per iter
    #pragma unroll
    for (int it = 0; it < 8; ++it) {
        int i = it * 256 + tid;
        int r = i >> 5;          // 32 x 16B segments per 512B row
        int s = i & 31;
        *reinterpret_cast<uint4*>(C + (size_t)(row0 + r) * H + s * 8) =
            *reinterpret_cast<const uint4*>(&cT[r][s * 8]);
    }
}

// ---------------- fold per-block partials into per-graph stats ----------------
// Graph b covers rows [gstart[b], gstart[b+1]) -> blocks n0/64 .. (n1-1)/64
// (~13 blocks). rel plane of block blk for graph b is b - bid[blk*64].
__global__ void k_stats_red(const float2* __restrict__ part, const int* __restrict__ bid,
                            const int* __restrict__ gstart,
                            float* __restrict__ gsum, float* __restrict__ gsumsq) {
    constexpr size_t PLANE = (size_t)NBLK * H;
    int b = blockIdx.x;
    int c = threadIdx.x;
    int n0 = gstart[b], n1 = gstart[b + 1];
    float s = 0.f, q = 0.f;
    if (n1 > n0) {
        int blo = n0 >> 6, bhi = (n1 - 1) >> 6;
        for (int blk = blo; blk <= bhi; ++blk) {
            int rel = b - bid[blk << 6];
            if (rel >= 0 && rel < 3) {
                float2 v = part[(size_t)rel * PLANE + (size_t)blk * H + c];
                s += v.x; q += v.y;
            }
        }
    }
    gsum[b * H + c]   = s;
    gsumsq[b * H + c] = q;
}

// ---------------- fused scale/shift + normalize + relu (+ residual) ----------------
template <bool RES>
__global__ void k_norm(const bf16_t* __restrict__ y, const bf16_t* __restrict__ resid,
                       const int* __restrict__ bid, const float* __restrict__ gsum,
                       const float* __restrict__ gsumsq, const float* __restrict__ countsf,
                       const float* __restrict__ gamma, const float* __restrict__ beta,
                       const float* __restrict__ msc, bf16_t* __restrict__ outp) {
    int idx = blockIdx.x * blockDim.x + threadIdx.x;  // over N*H/4
    if (idx >= N_NODES * (H / 4)) return;
    int n  = idx >> 6;      // 64 x ushort4 per row
    int f4 = idx & 63;
    int b  = bid[n];
    float rc = 1.0f / countsf[b];
    float4 s4  = reinterpret_cast<const float4*>(gsum)[b * 64 + f4];
    float4 q4  = reinterpret_cast<const float4*>(gsumsq)[b * 64 + f4];
    float4 g4  = reinterpret_cast<const float4*>(gamma)[f4];
    float4 be4 = reinterpret_cast<const float4*>(beta)[f4];
    float4 m4  = reinterpret_cast<const float4*>(msc)[f4];
    ushort4 yv = reinterpret_cast<const ushort4*>(y)[idx];

    auto nrm = [&](float s, float q, float ga, float be, float m, float yy) {
        float mean = s * rc, ex2 = q * rc;
        float mm   = mean * m;
        float var  = ex2 - 2.f * mean * mm + mm * mm;
        float a    = ga * rsqrtf(var + EPSV);
        return fmaxf(yy * a + (be - a * mm), 0.f);
    };
    float o0 = nrm(s4.x, q4.x, g4.x, be4.x, m4.x, bf2f(yv.x));
    float o1 = nrm(s4.y, q4.y, g4.y, be4.y, m4.y, bf2f(yv.y));
    float o2 = nrm(s4.z, q4.z, g4.z, be4.z, m4.z, bf2f(yv.z));
    float o3 = nrm(s4.w, q4.w, g4.w, be4.w, m4.w, bf2f(yv.w));
    if constexpr (RES) {
        ushort4 r = reinterpret_cast<const ushort4*>(resid)[idx];
        o0 += bf2f(r.x); o1 += bf2f(r.y); o2 += bf2f(r.z); o3 += bf2f(r.w);
    }
    ushort4 o;
    o.x = f2bf(o0); o.y = f2bf(o1); o.z = f2bf(o2); o.w = f2bf(o3);
    reinterpret_cast<ushort4*>(outp)[idx] = o;
}

// ---------------- pooling (sliced, 2-stage) + prediction head ----------------
__global__ void k_pool(const bf16_t* __restrict__ hf, const int* __restrict__ gstart,
                       float* pooled) {
    int b = blockIdx.x, sl = blockIdx.y, f = threadIdx.x;
    int n0 = gstart[b], n1 = gstart[b + 1];
    int cnt = n1 - n0;
    int lo = n0 + (int)((long long)cnt * sl / PSLICES);
    int hi = n0 + (int)((long long)cnt * (sl + 1) / PSLICES);
    if (lo >= hi) return;
    float s = 0.f;
    for (int n = lo; n < hi; ++n) s += bf2f(hf[(size_t)n * H + f]);
    atomicAdd(&pooled[b * H + f], s);
}

__global__ void k_pred(const float* __restrict__ pooled, const float* __restrict__ Wp,
                       const float* __restrict__ bp, float* __restrict__ outp) {
    __shared__ float row[H];
    int b = blockIdx.x;
    row[threadIdx.x] = pooled[b * H + threadIdx.x];
    __syncthreads();
    if (threadIdx.x < OUT_DIM) {
        float acc = bp[threadIdx.x];
        for (int f = 0; f < H; ++f) acc += row[f] * Wp[f * OUT_DIM + threadIdx.x];
        outp[b * OUT_DIM + threadIdx.x] = acc;
    }
}

extern "C" void kernel_launch(void* const* d_in, const int* in_sizes, int n_in,
                              void* d_out, int out_size, void* d_ws, size_t ws_size,
                              hipStream_t stream) {
    const float* h_in  = (const float*)d_in[0];
    const int*   src   = (const int*)d_in[1];
    const int*   dst   = (const int*)d_in[2];
    const int*   bid   = (const int*)d_in[3];
    const float* Wf    = (const float*)d_in[4];
    const float* bfv   = (const float*)d_in[5];
    const float* Wr    = (const float*)d_in[6];
    const float* br    = (const float*)d_in[7];
    const float* gamma = (const float*)d_in[8];
    const float* beta  = (const float*)d_in[9];
    const float* ms    = (const float*)d_in[10];
    const float* Wp    = (const float*)d_in[11];
    const float* bp    = (const float*)d_in[12];
    float* outp = (float*)d_out;

    char* w = (char*)d_ws;
    size_t off = 0;
    auto alloc = [&](size_t bytes) -> void* {
        void* p = w + off;
        off = (off + bytes + 255) & ~(size_t)255;
        return p;
    };
    bf16_t* bufA = (bf16_t*)alloc((size_t)N_PAD * H * 2);
    bf16_t* bufB = (bf16_t*)alloc((size_t)N_PAD * H * 2);
    bf16_t* bufC = (bf16_t*)alloc((size_t)N_PAD * H * 2);
    bf16_t* Wt0  = (bf16_t*)alloc((size_t)H * DIN * 2);
    bf16_t* Wt123= (bf16_t*)alloc((size_t)3 * H * H * 2);
    int* deg_out_i = (int*)alloc(N_NODES * 4);
    int* deg_in_i  = (int*)alloc(N_NODES * 4);
    float* dinv_src = (float*)alloc(N_NODES * 4);
    float* dinv_dst = (float*)alloc(N_NODES * 4);
    int* incl_tmp  = (int*)alloc(N_NODES * 4);
    int* bsums     = (int*)alloc(512 * 4);
    int* boffs     = (int*)alloc(512 * 4);
    int* row_start = (int*)alloc((N_NODES + 1) * 4);
    int* cursor    = (int*)alloc(N_NODES * 4);
    int* csr_src   = (int*)alloc(N_EDGES * 4);
    int* gstart    = (int*)alloc((NB + 1) * 4);
    float* countsf = (float*)alloc(NB * 4);
    float* gsum    = (float*)alloc((size_t)NB * H * 4);
    float* gsumsq  = (float*)alloc((size_t)NB * H * 4);
    float2* part   = (float2*)alloc((size_t)3 * NBLK * H * 8);   // 9.6 MB
    float* pooled  = (float*)alloc(NB * H * 4);

    if (off > ws_size) return;   // clean failure instead of OOB

    // hs (prescaled layer-0 input, [N][128] bf16) lives in bufB: it is fully
    // consumed by k_agg before k_gemm_mfma overwrites bufB.
    bf16_t* hs = bufB;

    const int nscan = (N_NODES + SCAN_B - 1) / SCAN_B;

    hipMemsetAsync(deg_out_i, 0, N_NODES * 4, stream);
    hipMemsetAsync(deg_in_i, 0, N_NODES * 4, stream);
    hipMemsetAsync(pooled, 0, NB * H * 4, stream);

    k_edge_deg<<<(N_EDGES + 255) / 256, 256, 0, stream>>>(src, dst, deg_out_i, deg_in_i);
    k_gstart<<<1, 256, 0, stream>>>(bid, gstart, countsf);
    k_dinv<<<(N_NODES + 255) / 256, 256, 0, stream>>>(deg_out_i, deg_in_i, dinv_src, dinv_dst);
    k_scan1<<<nscan, SCAN_B, 0, stream>>>(deg_in_i, incl_tmp, bsums);
    k_scan2<<<1, 512, 0, stream>>>(bsums, boffs, nscan);
    k_scan3<<<(N_NODES + 255) / 256, 256, 0, stream>>>(deg_in_i, incl_tmp, boffs, row_start, cursor);
    k_scatter<<<(N_EDGES + 255) / 256, 256, 0, stream>>>(src, dst, cursor, csr_src);
    k_wt_first<<<(H * DIN + 255) / 256, 256, 0, stream>>>(Wf, Wt0);
    k_wt_rest<<<(3 * H * H + 255) / 256, 256, 0, stream>>>(Wr, Wt123);

    const int aggGrid  = (N_NODES + 3) / 4;
    const int normGrid = (N_NODES * (H / 4) + 255) / 256;
    const int gemmGrid = NBLK;

    // ---- layer 0 ----
    k_prescale<<<(N_NODES * (DIN / 4) + 255) / 256, 256, 0, stream>>>(h_in, dinv_src, hs);
    k_agg<DIN, true><<<aggGrid, 256, 0, stream>>>(hs, nullptr, dinv_dst, row_start, csr_src, bufA);
    k_gemm_mfma<DIN><<<gemmGrid, 256, 0, stream>>>(bufA, Wt0, bfv, bid, bufB, part);
    k_stats_red<<<NB, H, 0, stream>>>(part, bid, gstart, gsum, gsumsq);
    k_norm<false><<<normGrid, 256, 0, stream>>>(bufB, nullptr, bid, gsum, gsumsq, countsf,
                                                gamma, beta, ms, bufC);

    // ---- layers 1..3 ----
    bf16_t* hx = bufC;
    bf16_t* f1 = bufA;
    bf16_t* f2 = bufB;
    for (int i = 1; i < 4; ++i) {
        k_agg<H, false><<<aggGrid, 256, 0, stream>>>(hx, dinv_src, dinv_dst, row_start, csr_src, f1);
        k_gemm_mfma<H><<<gemmGrid, 256, 0, stream>>>(f1, Wt123 + (size_t)(i - 1) * H * H,
                                                     br + (i - 1) * H, bid, f2, part);
        k_stats_red<<<NB, H, 0, stream>>>(part, bid, gstart, gsum, gsumsq);
        k_norm<true><<<normGrid, 256, 0, stream>>>(f2, hx, bid, gsum, gsumsq, countsf,
                                                   gamma + i * H, beta + i * H, ms + i * H, f1);
        bf16_t* nh = f1; f1 = hx; hx = nh;
    }

    k_pool<<<dim3(NB, PSLICES), H, 0, stream>>>(hx, gstart, pooled);
    k_pred<<<NB, H, 0, stream>>>(pooled, Wp, bp, outp);
}